// Round 14
// baseline (527.505 us; speedup 1.0000x reference)
//
#include <hip/hip_runtime.h>
#include <stdint.h>
#include <stddef.h>

#define NTOK 1552
#define DIMM 512
#define IFFC 1365
#define IFF2 2730
#define NW1 2816       // padded/permuted w1 output cols (2*1408)
#define GSTRIDE 1408   // geglu output row stride (bf16) = padded K of w2
#define BATCH 2
#define MALL (BATCH*NTOK)   // 3104
#define AZ 6           // attention j-chunks (256 keys each)
#define W2SK 3         // w2 splitK
#define EMSK 4         // embed splitK

typedef unsigned short u16;
typedef __attribute__((ext_vector_type(8))) short bf16x8;
typedef __attribute__((ext_vector_type(4))) float f32x4;

__device__ __forceinline__ u16 f2bf(float f){
  union { float f; uint32_t u; } v; v.f = f;
  uint32_t u = v.u;
  uint32_t r = (u + 0x7FFFu + ((u >> 16) & 1u)) >> 16;
  return (u16)r;
}
__device__ __forceinline__ float bf2f(u16 x){
  union { uint32_t u; float f; } v; v.u = ((uint32_t)x) << 16; return v.f;
}
__device__ __forceinline__ uint32_t pack2bf(float a, float b){
  return (uint32_t)f2bf(a) | ((uint32_t)f2bf(b) << 16);
}

// async global->LDS, 16B per lane; LDS dest is wave-uniform base (lane*16 implicit)
__device__ __forceinline__ void gload_lds16(const u16* g, u16* l){
  __builtin_amdgcn_global_load_lds((const __attribute__((address_space(1))) void*)g,
                                   (__attribute__((address_space(3))) void*)l, 16, 0, 0);
}

// ---------- prep: weight convert/transpose (blocks 0..14079) + embed LN1 (blocks 14080..17151) ----------
__global__ void prep_kernel(const float* s0,const float* s1,const float* s2,const float* s3,
                            const float* s4,const float* s5,const float* s6,const float* s7,
                            u16* d0,u16* d1,u16* d2,u16* d3,u16* d4,u16* d5,u16* d6,u16* d7,
                            const float* rna, const float* atac,
                            const float* g0e, const float* b0e,
                            const float* g1e, const float* b1e, u16* lnout)
{
  __shared__ float tile[32][33];
  __shared__ float rs_[4], rss_[4];
  int t = threadIdx.x;
  if (blockIdx.x >= 14080){
    int r = blockIdx.x - 14080;
    const float* x; const float* g; const float* bb;
    if (r < 1536){ x = rna + (size_t)r*1024; g = g0e; bb = b0e; }
    else { x = atac + (size_t)(r-1536)*1024; g = g1e; bb = b1e; }
    float2 xa = *(const float2*)(x + 2*t);
    float2 xb = *(const float2*)(x + 512 + 2*t);
    float s = xa.x+xa.y+xb.x+xb.y;
    float ss = xa.x*xa.x+xa.y*xa.y+xb.x*xb.x+xb.y*xb.y;
    #pragma unroll
    for (int off = 32; off >= 1; off >>= 1){ s += __shfl_xor(s, off); ss += __shfl_xor(ss, off); }
    int w = t >> 6;
    if ((t & 63) == 0){ rs_[w] = s; rss_[w] = ss; }
    __syncthreads();
    s = rs_[0]+rs_[1]+rs_[2]+rs_[3];
    ss = rss_[0]+rss_[1]+rss_[2]+rss_[3];
    float mu = s / 1024.f;
    float rstd = rsqrtf(ss / 1024.f - mu*mu + 1e-5f);
    float2 ga = *(const float2*)(g + 2*t);
    float2 gb = *(const float2*)(g + 512 + 2*t);
    float2 ba = *(const float2*)(bb + 2*t);
    float2 bbv = *(const float2*)(bb + 512 + 2*t);
    uint32_t* o32 = (uint32_t*)(lnout + (size_t)r*1024);
    o32[t]       = pack2bf((xa.x-mu)*rstd*ga.x + ba.x, (xa.y-mu)*rstd*ga.y + ba.y);
    o32[t + 256] = pack2bf((xb.x-mu)*rstd*gb.x + bbv.x, (xb.y-mu)*rstd*gb.y + bbv.y);
    return;
  }
  const float* srcs[8] = {s0,s1,s2,s3,s4,s5,s6,s7};
  u16* dsts[8] = {d0,d1,d2,d3,d4,d5,d6,d7};
  const int KT[8]   = {32,32,16,16,16,16,44,16};
  const int NT[8]   = {16,16,32,16,16,88,16,32};
  const int TC[8]   = {512,512,2048,1024,1024,5632,2816,512};
  const int K_[8]   = {1024,1024,512,512,512,512,1365,512};
  const int NSRC[8] = {512,512,1024,512,512,2730,512,1024};
  const int LDK[8]  = {1024,1024,512,512,512,512,1408,512};
  const int NOUT[8] = {512,512,1024,512,512,2816,512,1024};
  const int WS_[8]  = {0,0,512*1024,512*512,512*512,512*2730,1365*512,0};
  const int WT_[8]  = {0,0,1024*512,512*512,512*512,2816*512,512*1408,0};

  int bid = blockIdx.x;
  int seg = 0, base = 0;
  while (seg < 7 && bid >= base + TC[seg]) { base += TC[seg]; ++seg; }
  int loc = bid - base;
  int kt = KT[seg];
  int z = loc / (kt*NT[seg]); loc -= z*(kt*NT[seg]);
  int kb = (loc % kt) * 32, nb = (loc / kt) * 32;
  const float* w = srcs[seg] + (size_t)z * WS_[seg];
  u16* wt = dsts[seg] + (size_t)z * WT_[seg];
  int K = K_[seg], NS = NSRC[seg], ldk = LDK[seg], NO = NOUT[seg];

  {
    int k = t >> 3, n4 = (t & 7) * 4;
    int gk = kb + k;
    float4 v = make_float4(0.f,0.f,0.f,0.f);
    if (gk < K){
      if (seg != 5){
        int gn = nb + n4;
        if (gn + 4 <= NS){
          v = *(const float4*)(w + (size_t)gk*NS + gn);
        } else {
          float* pv = (float*)&v;
          #pragma unroll
          for (int i = 0; i < 4; ++i){ int n = gn + i; if (n < NS) pv[i] = w[(size_t)gk*NS + n]; }
        }
      } else {
        float* pv = (float*)&v;
        #pragma unroll
        for (int i = 0; i < 4; ++i){
          int n = nb + n4 + i;
          if (n < NO){
            int bb = n >> 7, rr = n & 127, g = rr >> 5, hh = rr & 31;
            int j = bb*64 + g*16 + (hh & 15);
            if (j < 1365) pv[i] = w[(size_t)gk*NS + ((hh < 16) ? j : 1365 + j)];
          }
        }
      }
    }
    tile[k][n4] = v.x; tile[k][n4+1] = v.y; tile[k][n4+2] = v.z; tile[k][n4+3] = v.w;
  }
  __syncthreads();
  if (t < 128){
    int n = t >> 2, k8 = (t & 3) * 8;
    int gn = nb + n, gk = kb + k8;
    if (gn < NO && gk < ldk){
      u16 sh[8];
      #pragma unroll
      for (int i = 0; i < 8; ++i) sh[i] = f2bf(tile[k8+i][n]);
      *(bf16x8*)(wt + (size_t)gn*ldk + gk) = *(bf16x8*)sh;
    }
  }
}

// ---- batched embed: splitK(4) add + bias + LN2 -> tok + layer-0 attn-LN -> xn;
//      blocks 3072..3103 copy fusion tokens + their layer-0 LN. float2 paths. ----
__global__ void embed_addln2(const float* __restrict__ part,
                             const float* __restrict__ rb, const float* __restrict__ ab,
                             const float* __restrict__ g0, const float* __restrict__ bt0,
                             const float* __restrict__ g1, const float* __restrict__ bt1,
                             const float* __restrict__ ag0, const float* __restrict__ ft,
                             float* __restrict__ tok, u16* __restrict__ xn)
{
  __shared__ float rs_[4], rss_[4];
  int t = threadIdx.x;
  int bid = blockIdx.x;
  int w = t >> 6;
  if (bid >= 3072){
    int idx = bid - 3072;
    int b = idx >> 4, rr = idx & 15;
    float2 v = *(const float2*)(ft + (size_t)rr*DIMM + 2*t);
    size_t row = (size_t)(b*NTOK + 768 + rr)*DIMM;
    *(float2*)(tok + row + 2*t) = v;
    float s = v.x + v.y, ss = v.x*v.x + v.y*v.y;
    #pragma unroll
    for (int off = 32; off >= 1; off >>= 1){ s += __shfl_xor(s, off); ss += __shfl_xor(ss, off); }
    if ((t & 63) == 0){ rs_[w] = s; rss_[w] = ss; }
    __syncthreads();
    s = rs_[0]+rs_[1]+rs_[2]+rs_[3];
    ss = rss_[0]+rss_[1]+rss_[2]+rss_[3];
    float mu = s / DIMM;
    float rstd = rsqrtf(ss / DIMM - mu*mu + 1e-5f);
    float2 ga = *(const float2*)(ag0 + 2*t);
    ((uint32_t*)(xn + row))[t] = pack2bf((v.x-mu)*rstd*ga.x, (v.y-mu)*rstd*ga.y);
    return;
  }
  int r = bid;
  int mod = (r >= 1536);
  int rl = mod ? r - 1536 : r;
  int b = rl / 768, rr = rl % 768;
  const float* bias = mod ? ab : rb;
  const float* g = mod ? g1 : g0;
  const float* bt = mod ? bt1 : bt0;
  const float* p0 = part + (size_t)r*DIMM + 2*t;
  float2 v = *(const float2*)(bias + 2*t);
  #pragma unroll
  for (int z = 0; z < EMSK; ++z){
    float2 pz = *(const float2*)(p0 + (size_t)z*3072*DIMM);
    v.x += pz.x; v.y += pz.y;
  }
  float s = v.x + v.y, ss = v.x*v.x + v.y*v.y;
  #pragma unroll
  for (int off = 32; off >= 1; off >>= 1){ s += __shfl_xor(s, off); ss += __shfl_xor(ss, off); }
  if ((t & 63) == 0){ rs_[w] = s; rss_[w] = ss; }
  __syncthreads();
  s = rs_[0]+rs_[1]+rs_[2]+rs_[3];
  ss = rss_[0]+rss_[1]+rss_[2]+rss_[3];
  float mu = s / DIMM;
  float rstd = rsqrtf(ss / DIMM - mu*mu + 1e-5f);
  size_t row = (size_t)(b*NTOK + (mod ? 784 : 0) + rr)*DIMM;
  float2 gv = *(const float2*)(g + 2*t);
  float2 btv = *(const float2*)(bt + 2*t);
  float t0 = (v.x - mu)*rstd*gv.x + btv.x;
  float t1 = (v.y - mu)*rstd*gv.y + btv.y;
  *(float2*)(tok + row + 2*t) = make_float2(t0, t1);
  float s2 = t0 + t1, ss2 = t0*t0 + t1*t1;
  #pragma unroll
  for (int off = 32; off >= 1; off >>= 1){ s2 += __shfl_xor(s2, off); ss2 += __shfl_xor(ss2, off); }
  __syncthreads();
  if ((t & 63) == 0){ rs_[w] = s2; rss_[w] = ss2; }
  __syncthreads();
  s2 = rs_[0]+rs_[1]+rs_[2]+rs_[3];
  ss2 = rss_[0]+rss_[1]+rss_[2]+rss_[3];
  float mu2 = s2 / DIMM;
  float rstd2 = rsqrtf(ss2 / DIMM - mu2*mu2 + 1e-5f);
  float2 aga = *(const float2*)(ag0 + 2*t);
  ((uint32_t*)(xn + row))[t] = pack2bf((t0-mu2)*rstd2*aga.x, (t1-mu2)*rstd2*aga.y);
}

// ---- residual-add (attention proj, broadcast row0) + FFN LN -> tok, xn (float2) ----
__global__ void resadd_ffnln(float* __restrict__ tok, const float* __restrict__ proj,
                             const float* __restrict__ g, u16* __restrict__ xn)
{
  int n = blockIdx.x, b = blockIdx.y;
  int pr = (n >= 768 && n < 784) ? (1 + n - 768) : 0;
  const float* p = proj + ((size_t)b*17 + pr)*DIMM;
  size_t row = (size_t)(b*NTOK + n)*DIMM;
  int t = threadIdx.x;
  float2 tv = *(const float2*)(tok + row + 2*t);
  float2 pv = *(const float2*)(p + 2*t);
  float v0 = tv.x + pv.x, v1 = tv.y + pv.y;
  *(float2*)(tok + row + 2*t) = make_float2(v0, v1);
  float s = v0 + v1, ss = v0*v0 + v1*v1;
  #pragma unroll
  for (int off = 32; off >= 1; off >>= 1){ s += __shfl_xor(s, off); ss += __shfl_xor(ss, off); }
  __shared__ float rs_[4], rss_[4];
  int w = t >> 6;
  if ((t & 63) == 0){ rs_[w] = s; rss_[w] = ss; }
  __syncthreads();
  s = rs_[0]+rs_[1]+rs_[2]+rs_[3];
  ss = rss_[0]+rss_[1]+rss_[2]+rss_[3];
  float mu = s / DIMM;
  float rstd = rsqrtf(ss / DIMM - mu*mu + 1e-5f);
  float2 gv = *(const float2*)(g + 2*t);
  ((uint32_t*)(xn + row))[t] = pack2bf((v0-mu)*rstd*gv.x, (v1-mu)*rstd*gv.y);
}

// ---- splitK(3)-add (FFN out) + next LN -> tok, xn (float2) ----
__global__ void skadd_ln(float* __restrict__ tok, const float* __restrict__ part,
                         const float* __restrict__ g, u16* __restrict__ xn)
{
  int r = blockIdx.x;
  size_t row = (size_t)r*DIMM;
  int t = threadIdx.x;
  float2 v = *(const float2*)(tok + row + 2*t);
  #pragma unroll
  for (int z = 0; z < W2SK; ++z){
    float2 pz = *(const float2*)(part + (size_t)z*MALL*DIMM + row + 2*t);
    v.x += pz.x; v.y += pz.y;
  }
  *(float2*)(tok + row + 2*t) = v;
  float s = v.x + v.y, ss = v.x*v.x + v.y*v.y;
  #pragma unroll
  for (int off = 32; off >= 1; off >>= 1){ s += __shfl_xor(s, off); ss += __shfl_xor(ss, off); }
  __shared__ float rs_[4], rss_[4];
  int w = t >> 6;
  if ((t & 63) == 0){ rs_[w] = s; rss_[w] = ss; }
  __syncthreads();
  s = rs_[0]+rs_[1]+rs_[2]+rs_[3];
  ss = rss_[0]+rss_[1]+rss_[2]+rss_[3];
  float mu = s / DIMM;
  float rstd = rsqrtf(ss / DIMM - mu*mu + 1e-5f);
  float2 gv = *(const float2*)(g + 2*t);
  ((uint32_t*)(xn + row))[t] = pack2bf((v.x-mu)*rstd*gv.x, (v.y-mu)*rstd*gv.y);
}

// ------- gemm512: 8-wave 128x128; 2-phase double-buffered global_load_lds staging.
//         B bf16 [N][ldk]; optional B-switch at row mswitch; splitK via grid.z;
//         optional GEGLU epilogue; optional V-colsum. OOB clamped (outputs masked). -------
__global__ __launch_bounds__(512) void gemm512(
    const u16* __restrict__ A, int lda,
    const u16* __restrict__ Bt, const u16* __restrict__ BtB, int mswitch, int ldk,
    float* __restrict__ C, int ldc, size_t Cz,
    u16* __restrict__ gout, float* __restrict__ csum,
    int M, int Nn, int K, int kchunk)
{
  __shared__ __align__(16) u16 As_lin[2][128*32];
  __shared__ __align__(16) u16 Bs_lin[2][128*32];
  __shared__ float colsum[2][128];
  const int t = threadIdx.x;
  const int lane = t & 63;
  const int w = t >> 6;
  const int wr = (w >> 2) * 64;
  const int wc = (w & 3) * 32;
  const int row0 = blockIdx.x * 128, col0 = blockIdx.y * 128;
  if (BtB && row0 >= mswitch) Bt = BtB;
  const int z = blockIdx.z;
  const int kbeg = z * kchunk;
  const int kend = (kbeg + kchunk < K) ? (kbeg + kchunk) : K;
  C += (size_t)z * Cz;
  const int l15 = lane & 15;
  const int l4 = (lane >> 4) * 8;
  const int sr = t >> 2, sc8 = (t & 3) * 8;
  int gr_s = row0 + sr; if (gr_s >= M) gr_s = M - 1;
  int gc_s = col0 + sr; if (gc_s >= Nn) gc_s = Nn - 1;
  const u16* Ag = A + (size_t)gr_s*lda + sc8;
  const u16* Bg = Bt + (size_t)gc_s*ldk + sc8;
  const int wb = w * 512;

  f32x4 acc[4][2];
  #pragma unroll
  for (int m = 0; m < 4; ++m)
    #pragma unroll
    for (int n = 0; n < 2; ++n)
      #pragma unroll
      for (int j = 0; j < 4; ++j) acc[m][n][j] = 0.f;

  gload_lds16(Ag + kbeg, &As_lin[0][wb]);
  gload_lds16(Bg + kbeg, &Bs_lin[0][wb]);
  __syncthreads();

  int cur = 0;
  for (int k0 = kbeg; k0 < kend; k0 += 32) {
    int k1 = k0 + 32;
    if (k1 < kend){
      gload_lds16(Ag + k1, &As_lin[cur^1][wb]);
      gload_lds16(Bg + k1, &Bs_lin[cur^1][wb]);
    }
    const u16* Ar = &As_lin[cur][0];
    const u16* Br = &Bs_lin[cur][0];
    bf16x8 af[4], bfr[2];
    #pragma unroll
    for (int m = 0; m < 4; ++m) af[m]  = *(const bf16x8*)(&Ar[(wr + m*16 + l15)*32 + l4]);
    #pragma unroll
    for (int n = 0; n < 2; ++n) bfr[n] = *(const bf16x8*)(&Br[(wc + n*16 + l15)*32 + l4]);
    #pragma unroll
    for (int m = 0; m < 4; ++m)
      #pragma unroll
      for (int n = 0; n < 2; ++n)
        acc[m][n] = __builtin_amdgcn_mfma_f32_16x16x32_bf16(af[m], bfr[n], acc[m][n], 0, 0, 0);
    __syncthreads();
    cur ^= 1;
  }
  const int rb = (lane >> 4) * 4;
  if (gout){
    int jcol = (col0 >> 1) + (w & 3)*16 + l15;
    #pragma unroll
    for (int m = 0; m < 4; ++m){
      int gr0 = row0 + wr + m*16 + rb;
      #pragma unroll
      for (int j = 0; j < 4; ++j){
        int gr = gr0 + j;
        if (gr < M){
          float gt = acc[m][1][j];
          float ge = 0.5f * gt * (1.0f + erff(gt * 0.70710678118654752f));
          gout[(size_t)gr*GSTRIDE + jcol] = f2bf(ge * acc[m][0][j]);
        }
      }
    }
  } else {
    #pragma unroll
    for (int m = 0; m < 4; ++m){
      int gr0 = row0 + wr + m*16 + rb;
      #pragma unroll
      for (int n = 0; n < 2; ++n){
        int gc = col0 + wc + n*16 + l15;
        if (gc >= Nn) continue;
        #pragma unroll
        for (int j = 0; j < 4; ++j){
          int gr = gr0 + j;
          if (gr < M) C[(size_t)gr*ldc + gc] = acc[m][n][j];
        }
      }
    }
  }
  if (csum && col0 >= 512){
    if (t < 256) colsum[t>>7][t&127] = 0.f;
    __syncthreads();
    #pragma unroll
    for (int n = 0; n < 2; ++n){
      float lv0 = 0.f, lv1 = 0.f;
      #pragma unroll
      for (int m = 0; m < 4; ++m){
        int gr0 = row0 + wr + m*16 + rb;
        #pragma unroll
        for (int j = 0; j < 4; ++j){
          float v = acc[m][n][j];
          if (gr0 + j < NTOK) lv0 += v; else lv1 += v;
        }
      }
      int lc = wc + n*16 + l15;
      atomicAdd(&colsum[0][lc], lv0);
      atomicAdd(&colsum[1][lc], lv1);
    }
    __syncthreads();
    if (t < 256){
      int bb = t>>7, c = t&127;
      csum[((size_t)(bb*25) + blockIdx.x)*512 + (col0 - 512) + c] = colsum[bb][c];
    }
  }
}

// ------- fused attention, flash-split: one block per (h, b, qi, jz); 256 keys/block -------
__global__ __launch_bounds__(256) void fused_attn(
    const u16* __restrict__ xn, const u16* __restrict__ wqt,
    const float* __restrict__ kv, float* __restrict__ apart)
{
  int h = blockIdx.x, b = blockIdx.y;
  int qi = blockIdx.z / AZ, jz = blockIdx.z % AZ;
  int t = threadIdx.x;
  int lane = t & 63, wid = t >> 6;
  __shared__ float xs[512];
  __shared__ float qs[64];
  __shared__ float pl[256];
  __shared__ float red[4][64];
  __shared__ float redm[4];

  {
    int row = b*NTOK + 768 + qi;
    const u16* xr = xn + (size_t)row*DIMM;
    xs[t] = bf2f(xr[t]);
    xs[t+256] = bf2f(xr[t+256]);
  }
  __syncthreads();

  {
    const u16* wrr = wqt + (size_t)(h*64 + lane)*DIMM + wid*128;
    float a = 0.f;
    #pragma unroll
    for (int k = 0; k < 128; k += 8){
      bf16x8 wv = *(const bf16x8*)(wrr + k);
      int kb = wid*128 + k;
      #pragma unroll
      for (int i = 0; i < 8; ++i) a += xs[kb+i] * bf2f((u16)wv[i]);
    }
    red[wid][lane] = a;
  }
  __syncthreads();
  if (t < 64) qs[t] = (red[0][t] + red[1][t] + red[2][t] + red[3][t]) * 0.125f;
  __syncthreads();

  int jj = jz*256 + t;
  int j = (jj < 768) ? jj : jj + 16;
  float a = 0.f;
  {
    const float* kr = kv + ((size_t)(b*NTOK + j))*1024 + h*64;
    #pragma unroll
    for (int d = 0; d < 64; d += 4){
      float4 kd = *(const float4*)(kr + d);
      a += qs[d]*kd.x + qs[d+1]*kd.y + qs[d+2]*kd.z + qs[d+3]*kd.w;
    }
  }

  float m = a;
  #pragma unroll
  for (int off = 32; off >= 1; off >>= 1) m = fmaxf(m, __shfl_xor(m, off));
  if (lane == 0) redm[wid] = m;
  __syncthreads();
  m = fmaxf(fmaxf(redm[0], redm[1]), fmaxf(redm[2], redm[3]));
  float p = __expf(a - m);
  pl[t] = p;
  float sq = p;
  #pragma unroll
  for (int off = 32; off >= 1; off >>= 1) sq += __shfl_xor(sq, off);
  if (lane == 0) redm[wid] = sq;
  __syncthreads();

  {
    int j0 = wid * 64;
    const float* vb = kv + ((size_t)(b*NTOK + jz*256 + j0 + ((jz*256 + j0 >= 768) ? 16 : 0)))*1024
                      + 512 + h*64 + lane;
    float a0=0.f, a1=0.f, a2=0.f, a3=0.f;
    #pragma unroll 4
    for (int i = 0; i < 64; i += 4){
      const float* vp = vb + (size_t)i*1024;
      a0 += pl[j0+i]   * vp[0];
      a1 += pl[j0+i+1] * vp[1024];
      a2 += pl[j0+i+2] * vp[2048];
      a3 += pl[j0+i+3] * vp[3072];
    }
    red[wid][lane] = a0+a1+a2+a3;
  }
  __syncthreads();
  float* po = apart + ((((size_t)jz*BATCH + b)*8 + h)*16 + qi) * 68;
  if (t < 64) po[t] = red[0][t] + red[1][t] + red[2][t] + red[3][t];
  else if (t == 64) po[64] = m;
  else if (t == 65) po[65] = redm[0] + redm[1] + redm[2] + redm[3];
}

// ------- attn_out: merge flash partials + colmean row + wo-projection, fused -------
__global__ __launch_bounds__(256) void attn_out(
    const float* __restrict__ apart, const float* __restrict__ csum,
    const u16* __restrict__ wot, float* __restrict__ proj)
{
  int colchunk = blockIdx.x;
  int b = blockIdx.y;
  int rg = blockIdx.z;
  int r0 = (rg == 0) ? 0 : (1 + 4*rg);
  int nr = (rg == 0) ? 5 : 4;
  __shared__ float zbl[5][512];
  __shared__ float red[4][64];
  int t = threadIdx.x;

  for (int rr = 0; rr < nr; ++rr){
    int r = r0 + rr;
    if (r == 0){
      for (int c = t; c < 512; c += 256){
        float s = 0.f;
        #pragma unroll
        for (int bx = 0; bx < 25; ++bx) s += csum[((size_t)(b*25)+bx)*512 + c];
        zbl[rr][c] = s * (1.0f/1552.0f);
      }
    } else {
      int qi = r - 1;
      for (int c = t; c < 512; c += 256){
        int h = c >> 6, d = c & 63;
        size_t base = ((size_t)b*8 + h)*16 + qi;
        float mz[AZ], sz[AZ];
        float M = -3.4e38f;
        #pragma unroll
        for (int z = 0; z < AZ; ++z){
          const float* po = apart + ((size_t)z*BATCH*8*16 + base)*68;
          mz[z] = po[64]; sz[z] = po[65];
          M = fmaxf(M, mz[z]);
        }
        float S = 0.f, O = 0.f;
        #pragma unroll
        for (int z = 0; z < AZ; ++z){
          const float* po = apart + ((size_t)z*BATCH*8*16 + base)*68;
          float wz = __expf(mz[z] - M);
          S += sz[z]*wz; O += po[d]*wz;
        }
        zbl[rr][c] = O / S;
      }
    }
  }
  __syncthreads();

  int col = colchunk*64 + (t & 63);
  int kq = t >> 6;
  const u16* wrow = wot + (size_t)col*512 + kq*128;
  for (int rr = 0; rr < nr; ++rr){
    float a = 0.f;
    #pragma unroll
    for (int k = 0; k < 128; k += 8){
      bf16x8 wv = *(const bf16x8*)(wrow + k);
      #pragma unroll
      for (int i = 0; i < 8; ++i) a += zbl[rr][kq*128 + k + i] * bf2f((u16)wv[i]);
    }
    red[kq][t & 63] = a;
    __syncthreads();
    if (t < 64)
      proj[((size_t)(b*17) + r0 + rr)*DIMM + colchunk*64 + t] =
        red[0][t] + red[1][t] + red[2][t] + red[3][t];
    __syncthreads();
  }
}

// ------- pool_final: csum->mv, LN+q2, 16-key attention, wo-matvec + residual, fused -------
__global__ __launch_bounds__(256) void pool_final(
    const float* __restrict__ csum, const float* __restrict__ rt,
    const float* __restrict__ pg, const float* __restrict__ wq,
    const float* __restrict__ kv, const float* __restrict__ wo,
    float* __restrict__ out)
{
  int colchunk = blockIdx.x;
  int br = blockIdx.y; int b = br/3, r = br%3;
  __shared__ float ys[512];
  __shared__ float q2l[512];
  __shared__ float qred[2][512];
  __shared__ float fred[16][64];
  __shared__ float sm[8][16];
  __shared__ float pn[8][16];
  __shared__ float rs_[4], rss_[4];
  int t = threadIdx.x;

  if (r < 2){
    float a0 = 0.f, a1 = 0.f;
    #pragma unroll
    for (int bx = 0; bx < 25; ++bx){
      a0 += csum[((size_t)(b*25)+bx)*512 + t];
      a1 += csum[((size_t)(b*25)+bx)*512 + t + 256];
    }
    ys[t] = a0 * (1.0f/1552.0f);
    ys[t+256] = a1 * (1.0f/1552.0f);
    __syncthreads();
  } else {
    const float* x = rt + 2*DIMM;
    float v0 = x[t], v1 = x[t+256];
    float s = v0 + v1, ss = v0*v0 + v1*v1;
    #pragma unroll
    for (int off = 32; off >= 1; off >>= 1){ s += __shfl_xor(s, off); ss += __shfl_xor(ss, off); }
    int w = t >> 6;
    if ((t & 63) == 0){ rs_[w] = s; rss_[w] = ss; }
    __syncthreads();
    s = rs_[0]+rs_[1]+rs_[2]+rs_[3];
    ss = rss_[0]+rss_[1]+rss_[2]+rss_[3];
    float mu = s / DIMM;
    float rstd = rsqrtf(ss / DIMM - mu*mu + 1e-5f);
    ys[t]     = (v0 - mu)*rstd*pg[t];
    ys[t+256] = (v1 - mu)*rstd*pg[t+256];
    __syncthreads();
    {
      int c4 = (t & 127) * 4;
      int kq = t >> 7;
      float ax=0.f, ay=0.f, az=0.f, aw=0.f;
      #pragma unroll 8
      for (int k = kq*256; k < kq*256 + 256; ++k){
        float yv = ys[k];
        float4 w4 = *(const float4*)(wq + (size_t)k*512 + c4);
        ax += yv*w4.x; ay += yv*w4.y; az += yv*w4.z; aw += yv*w4.w;
      }
      qred[kq][c4] = ax; qred[kq][c4+1] = ay; qred[kq][c4+2] = az; qred[kq][c4+3] = aw;
    }
    __syncthreads();
    q2l[t]     = (qred[0][t]     + qred[1][t])     * 0.125f;
    q2l[t+256] = (qred[0][t+256] + qred[1][t+256]) * 0.125f;
    __syncthreads();
    if (t < 128){
      int h = t >> 4, j = t & 15;
      const float* kr = kv + ((size_t)(b*NTOK + 768 + j))*1024 + h*64;
      float a = 0.f;
      #pragma unroll
      for (int d = 0; d < 64; ++d) a += q2l[h*64 + d] * kr[d];
      sm[h][j] = a;
    }
    __syncthreads();
    if (t < 8){
      float m = -3.4e38f;
      #pragma unroll
      for (int j = 0; j < 16; ++j) m = fmaxf(m, sm[t][j]);
      float e[16]; float s2 = 0.f;
      #pragma unroll
      for (int j = 0; j < 16; ++j){ e[j] = __expf(sm[t][j] - m); s2 += e[j]; }
      float inv = 1.0f / s2;
      #pragma unroll
      for (int j = 0; j < 16; ++j) pn[t][j] = e[j] * inv;
    }
    __syncthreads();
    {
      int c0 = t, c1 = t + 256;
      int h0 = c0 >> 6, h1 = c1 >> 6;
      float a0 = 0.f, a1 = 0.f;
      #pragma unroll
      for (int j = 0; j < 16; ++j){
        const float* vr = kv + ((size_t)(b*NTOK + 768 + j))*1024 + 512;
        a0 += pn[h0][j] * vr[c0];
        a1 += pn[h1][j] * vr[c1];
      }
      ys[c0] = a0; ys[c1] = a1;
    }
    __syncthreads();
  }

  {
    int c4l = (t & 15) * 4;
    int c4 = colchunk*64 + c4l;
    int kq = t >> 4;
    float ax=0.f, ay=0.f, az=0.f, aw=0.f;
    #pragma unroll 8
    for (int k = kq*32; k < kq*32 + 32; ++k){
      float yv = ys[k];
      float4 w4 = *(const float4*)(wo + (size_t)k*512 + c4);
      ax += yv*w4.x; ay += yv*w4.y; az += yv*w4.z; aw += yv*w4.w;
    }
    fred[kq][c4l] = ax; fred[kq][c4l+1] = ay; fred[kq][c4l+2] = az; fred[kq][c4l+3] = aw;
  }
  __syncthreads();
  if (t < 64){
    float a = 0.f;
    #pragma unroll
    for (int kq = 0; kq < 16; ++kq) a += fred[kq][t];
    int c = colchunk*64 + t;
    out[(size_t)br*DIMM + c] = a + rt[(size_t)r*DIMM + c];
  }
}

// =================================================================
extern "C" void kernel_launch(void* const* d_in, const int* in_sizes, int n_in,
                              void* d_out, int out_size, void* d_ws, size_t ws_size,
                              hipStream_t stream)
{
  const float* rna        = (const float*)d_in[0];
  const float* atac       = (const float*)d_in[1];
  const float* rna_ln1_g  = (const float*)d_in[2];
  const float* rna_ln1_b  = (const float*)d_in[3];
  const float* rna_w      = (const float*)d_in[4];
  const float* rna_b      = (const float*)d_in[5];
  const float* rna_ln2_g  = (const float*)d_in[6];
  const float* rna_ln2_b  = (const float*)d_in[7];
  const float* atac_ln1_g = (const float*)d_in[8];
  const float* atac_ln1_b = (const float*)d_in[9];
  const float* atac_w     = (const float*)d_in[10];
  const float* atac_b     = (const float*)d_in[11];
  const float* atac_ln2_g = (const float*)d_in[12];
  const float* atac_ln2_b = (const float*)d_in[13];
  const float* fusion_tok = (const float*)d_in[14];
  const float* lay_ag     = (const float*)d_in[15];
  const float* lay_wq     = (const float*)d_in[16];
  const float* lay_wkv    = (const float*)d_in[17];
  const float* lay_wo     = (const float*)d_in[18];
  const float* lay_fg     = (const float*)d_in[19];
  const float* lay_w1     = (const float*)d_in[20];
  const float* lay_w2     = (const float*)d_in[21];
  const float* final_g    = (const float*)d_in[22];
  const float* ret_tok    = (const float*)d_in[23];
  const float* pool_g     = (const float*)d_in[24];
  const float* pool_wq    = (const float*)d_in[25];
  const float* pool_wkv   = (const float*)d_in[26];
  const float* pool_wo    = (const float*)d_in[27];

  uint8_t* ws = (uint8_t*)d_ws;
  size_t off = 0;
  auto carve = [&](size_t bytes) -> uint8_t* {
    uint8_t* p = ws + off;
    off += (bytes + 255) & ~(size_t)255;
    return p;
  };
  // bf16 weights
  u16* rna_wt   = (u16*)carve((size_t)512*1024*2);
  u16* atac_wt  = (u16*)carve((size_t)512*1024*2);
  u16* wkvt     = (u16*)carve((size_t)4*1024*512*2);
  u16* wqt      = (u16*)carve((size_t)4*512*512*2);
  u16* wot      = (u16*)carve((size_t)4*512*512*2);
  u16* w1t      = (u16*)carve((size_t)4*NW1*512*2);
  u16* w2t      = (u16*)carve((size_t)4*512*GSTRIDE*2);
  u16* pool_wkvt= (u16*)carve((size_t)1024*512*2);
  // activations
  float* tok   = (float*)carve((size_t)MALL * DIMM * 4);
  u16*   xn    = (u16*)  carve((size_t)MALL * DIMM * 2);
  float* kv    = (float*)carve((size_t)MALL * 1024 * 4);
  u16*   lnbuf = (u16*)  carve((size_t)3072 * 1024 * 2);
  float* proj  = (float*)carve((size_t)BATCH*17*DIMM * 4);
  float* csum  = (float*)carve((size_t)BATCH*25*512 * 4);
  float* apart = (float*)carve((size_t)AZ*BATCH*8*16*68 * 4);
  u16*   gbuf  = (u16*)  carve((size_t)MALL * GSTRIDE * 2);
  size_t skelems = (size_t)EMSK*3072*512;
  float* skpart= (float*)carve(skelems * 4);
  (void)ws_size;

  // ---- prep: weight conversion + embed LN1 (one dispatch) ----
  prep_kernel<<<14080 + 3072, 256, 0, stream>>>(
      rna_w, atac_w, lay_wkv, lay_wq, lay_wo, lay_w1, lay_w2, pool_wkv,
      rna_wt, atac_wt, wkvt, wqt, wot, w1t, w2t, pool_wkvt,
      rna, atac, rna_ln1_g, rna_ln1_b, atac_ln1_g, atac_ln1_b, lnbuf);

  // ---- embed GEMM (splitK 4) + addln2 (incl. fusion tokens + layer-0 LN) ----
  gemm512<<<dim3(24, 4, EMSK), 512, 0, stream>>>(lnbuf, 1024, rna_wt, atac_wt, 1536, 1024,
                                                 skpart, 512, (size_t)3072*512, nullptr, nullptr,
                                                 3072, 512, 1024, 1024/EMSK);
  embed_addln2<<<3104, 256, 0, stream>>>(skpart, rna_b, atac_b, rna_ln2_g, rna_ln2_b,
                                         atac_ln2_g, atac_ln2_b, lay_ag, fusion_tok, tok, xn);

  // ---- transformer layers ----
  for (int l = 0; l < 4; ++l){
    const float* fg  = lay_fg + (size_t)l*DIMM;
    const float* gnext = (l < 3) ? (lay_ag + (size_t)(l+1)*DIMM) : final_g;
    const u16* wkvt_l = wkvt + (size_t)l*1024*512;
    const u16* wqt_l  = wqt  + (size_t)l*512*512;
    const u16* wot_l  = wot  + (size_t)l*512*512;
    const u16* w1t_l  = w1t  + (size_t)l*NW1*512;
    const u16* w2t_l  = w2t  + (size_t)l*512*GSTRIDE;

    gemm512<<<dim3(25, 8, 1), 512, 0, stream>>>(xn, 512, wkvt_l, nullptr, 0, 512,
                                                kv, 1024, 0, nullptr, csum, MALL, 1024, 512, 512);
    fused_attn<<<dim3(8, BATCH, 16*AZ), 256, 0, stream>>>(xn, wqt_l, kv, apart);
    attn_out<<<dim3(8, BATCH, 4), 256, 0, stream>>>(apart, csum, wot_l, proj);
    resadd_ffnln<<<dim3(NTOK, BATCH), 256, 0, stream>>>(tok, proj, fg, xn);
    gemm512<<<dim3(25, 22, 1), 512, 0, stream>>>(xn, 512, w1t_l, nullptr, 0, 512,
                                                 nullptr, 0, 0, gbuf, nullptr, MALL, NW1, 512, 512);
    gemm512<<<dim3(25, 4, W2SK), 512, 0, stream>>>(gbuf, GSTRIDE, w2t_l, nullptr, 0, GSTRIDE,
                                                   skpart, 512, (size_t)MALL*512, nullptr, nullptr,
                                                   MALL, 512, GSTRIDE, 480);
    skadd_ln<<<MALL, 256, 0, stream>>>(tok, skpart, gnext, xn);
  }

  // ---- pooling (xn holds final-LN tokens) ----
  gemm512<<<dim3(25, 8, 1), 512, 0, stream>>>(xn, 512, pool_wkvt, nullptr, 0, 512,
                                              kv, 1024, 0, nullptr, csum, MALL, 1024, 512, 512);
  pool_final<<<dim3(8, 6), 256, 0, stream>>>(csum, ret_tok, pool_g, pool_wq, kv, pool_wo,
                                             (float*)d_out);
}